// Round 1
// baseline (208.251 us; speedup 1.0000x reference)
//
#include <hip/hip_runtime.h>
#include <math.h>

// CornerBoundingBoxEMDLoss: min-cost 8x8 assignment per batch.
// v2: one batch per LANE (not per wave). Full Held-Karp table f[256] and the
// 8x8 distance matrix live in per-lane VGPRs via total unrolling (every index
// compile-time constant -> SROA to registers). Zero cross-lane traffic:
// no shfl, no ds_swizzle, no LDS, no barriers. 4096 batches -> 64 waves,
// total wave-instruction issue drops ~20x vs the wave-per-batch version.
// __launch_bounds__(64,1): 1 wave/SIMD floor -> up to 512 VGPRs, no spill
// at the ~210-register liveness peak (f[] live set ~140 + d[64]).

#define INF 1e30f

__global__ __launch_bounds__(64, 1) void emd8_lane_kernel(
    const float* __restrict__ pred,
    const float* __restrict__ targ,
    float* __restrict__ out, int B) {

    const int b = blockIdx.x * 64 + (int)threadIdx.x;
    if (b >= B) return;

    // ---- Load this batch's 24+24 floats as 6+6 float4 (16B, aligned: 96B/row) ----
    float p[24], t[24];
    const float4* __restrict__ p4 = (const float4*)(pred + (size_t)b * 24);
    const float4* __restrict__ t4 = (const float4*)(targ + (size_t)b * 24);
    #pragma unroll
    for (int q = 0; q < 6; ++q) {
        const float4 a = p4[q];
        p[q * 4 + 0] = a.x; p[q * 4 + 1] = a.y;
        p[q * 4 + 2] = a.z; p[q * 4 + 3] = a.w;
        const float4 c = t4[q];
        t[q * 4 + 0] = c.x; t[q * 4 + 1] = c.y;
        t[q * 4 + 2] = c.z; t[q * 4 + 3] = c.w;
    }

    // ---- 8x8 Euclidean distance matrix, register-resident ----
    float d[64];
    #pragma unroll
    for (int i = 0; i < 8; ++i) {
        #pragma unroll
        for (int j = 0; j < 8; ++j) {
            const float dx = p[i * 3 + 0] - t[j * 3 + 0];
            const float dy = p[i * 3 + 1] - t[j * 3 + 1];
            const float dz = p[i * 3 + 2] - t[j * 3 + 2];
            d[i * 8 + j] = sqrtf(dx * dx + dy * dy + dz * dz);
        }
    }

    // ---- Held-Karp: f[m] = min cost assigning pred rows 0..popc(m)-1 to
    // target-column subset m. Ascending m is a valid order (m^(1<<j) < m).
    // Row accumulation order is 0..7 ascending -> same FP association as ref.
    float f[256];
    f[0] = 0.0f;
    #pragma unroll
    for (int m = 1; m < 256; ++m) {
        const int row8 = (__builtin_popcount(m) - 1) * 8;  // folds per unrolled m
        float best = INF;
        #pragma unroll
        for (int j = 0; j < 8; ++j) {
            if ((m >> j) & 1)   // folds away after outer unroll
                best = fminf(best, f[m ^ (1 << j)] + d[row8 + j]);
        }
        f[m] = best;
    }

    out[b] = f[255];  // coalesced 4B store
}

extern "C" void kernel_launch(void* const* d_in, const int* in_sizes, int n_in,
                              void* d_out, int out_size, void* d_ws, size_t ws_size,
                              hipStream_t stream) {
    const float* pred = (const float*)d_in[0];
    const float* targ = (const float*)d_in[1];
    float* out = (float*)d_out;
    const int B = in_sizes[0] / 24;          // [B, 8, 3]
    const int grid = (B + 63) / 64;          // one batch per lane, one wave per block
    emd8_lane_kernel<<<grid, 64, 0, stream>>>(pred, targ, out, B);
}

// Round 2
// 60.116 us; speedup vs baseline: 3.4642x; 3.4642x over previous
//
#include <hip/hip_runtime.h>
#include <math.h>

// CornerBoundingBoxEMDLoss: min-cost 8x8 assignment per batch.
// v3: one batch per LANE, Held-Karp DP fully register-resident.
// v2 failed because a plain "#pragma unroll" on the 255-iteration mask loop
// was refused by the unroll heuristic -> f[256]/d[64] runtime-indexed ->
// scratch (VGPR_Count=32, 8MB of scratch HBM traffic, 244us).
// v3 forces total unrolling with divide-and-conquer template recursion:
// every index is a compile-time constant after inlining, so SROA promotes
// all arrays to VGPRs. Zero cross-lane traffic, zero LDS, zero scratch.

#define INF 1e30f

// f[M] = min cost of assigning pred rows 0..popc(M)-1 to target-column set M.
// Reads only f[M ^ bit] with M^bit < M (already computed), writes f[M].
template<int M>
__device__ __forceinline__ void dp_one(float (&f)[256], const float (&d)[64]) {
    constexpr int row8 = (__builtin_popcount((unsigned)M) - 1) * 8;
    float best = INF;
    if constexpr ((M & 1)   != 0) best = fminf(best, f[M ^ 1]   + d[row8 + 0]);
    if constexpr ((M & 2)   != 0) best = fminf(best, f[M ^ 2]   + d[row8 + 1]);
    if constexpr ((M & 4)   != 0) best = fminf(best, f[M ^ 4]   + d[row8 + 2]);
    if constexpr ((M & 8)   != 0) best = fminf(best, f[M ^ 8]   + d[row8 + 3]);
    if constexpr ((M & 16)  != 0) best = fminf(best, f[M ^ 16]  + d[row8 + 4]);
    if constexpr ((M & 32)  != 0) best = fminf(best, f[M ^ 32]  + d[row8 + 5]);
    if constexpr ((M & 64)  != 0) best = fminf(best, f[M ^ 64]  + d[row8 + 6]);
    if constexpr ((M & 128) != 0) best = fminf(best, f[M ^ 128] + d[row8 + 7]);
    f[M] = best;
}

// Divide-and-conquer over mask range: recursion depth ~8 (inliner-safe),
// emits dp_one<1> .. dp_one<255> in ascending order.
template<int Lo, int Hi>
__device__ __forceinline__ void dp_range(float (&f)[256], const float (&d)[64]) {
    if constexpr (Lo == Hi) {
        dp_one<Lo>(f, d);
    } else {
        constexpr int Mid = (Lo + Hi) / 2;
        dp_range<Lo, Mid>(f, d);
        dp_range<Mid + 1, Hi>(f, d);
    }
}

__global__ __launch_bounds__(64, 1) void emd8_lane_kernel(
    const float* __restrict__ pred,
    const float* __restrict__ targ,
    float* __restrict__ out, int B) {

    const int b = blockIdx.x * 64 + (int)threadIdx.x;
    if (b >= B) return;

    // ---- Load this batch's 24+24 floats as 6+6 float4 (96B/batch, 16B-aligned) ----
    float p[24], t[24];
    const float4* __restrict__ p4 = (const float4*)(pred + (size_t)b * 24);
    const float4* __restrict__ t4 = (const float4*)(targ + (size_t)b * 24);
    #pragma unroll
    for (int q = 0; q < 6; ++q) {
        const float4 a = p4[q];
        p[q * 4 + 0] = a.x; p[q * 4 + 1] = a.y;
        p[q * 4 + 2] = a.z; p[q * 4 + 3] = a.w;
        const float4 c = t4[q];
        t[q * 4 + 0] = c.x; t[q * 4 + 1] = c.y;
        t[q * 4 + 2] = c.z; t[q * 4 + 3] = c.w;
    }

    // ---- 8x8 Euclidean distance matrix (constant-indexed -> registers) ----
    float d[64];
    #pragma unroll
    for (int i = 0; i < 8; ++i) {
        #pragma unroll
        for (int j = 0; j < 8; ++j) {
            const float dx = p[i * 3 + 0] - t[j * 3 + 0];
            const float dy = p[i * 3 + 1] - t[j * 3 + 1];
            const float dz = p[i * 3 + 2] - t[j * 3 + 2];
            d[i * 8 + j] = sqrtf(dx * dx + dy * dy + dz * dz);
        }
    }

    // ---- Held-Karp over all 255 nonzero masks, fully unrolled via templates.
    // Row accumulation order 0..7 ascending: same FP association as the
    // verified v1/v2 kernels (absmax 0.0).
    float f[256];
    f[0] = 0.0f;
    dp_range<1, 255>(f, d);

    out[b] = f[255];  // coalesced 4B store
}

extern "C" void kernel_launch(void* const* d_in, const int* in_sizes, int n_in,
                              void* d_out, int out_size, void* d_ws, size_t ws_size,
                              hipStream_t stream) {
    const float* pred = (const float*)d_in[0];
    const float* targ = (const float*)d_in[1];
    float* out = (float*)d_out;
    const int B = in_sizes[0] / 24;          // [B, 8, 3]
    const int grid = (B + 63) / 64;          // one batch per lane, one wave per block
    emd8_lane_kernel<<<grid, 64, 0, stream>>>(pred, targ, out, B);
}